// Round 2
// baseline (118.686 us; speedup 1.0000x reference)
//
#include <hip/hip_runtime.h>

#define GH 52
#define GW 52
#define NB 5
#define NBOX (GH*GW*NB)      // 13520
#define SCALE 8.0f           // 416/52
#define NORMY 416.0f
#define IOU_T 0.4f

#define TS 8                 // interior tile (cells)
#define HS (TS+2)            // halo tile 10x10
#define TBOX (HS*HS*NB)      // 500 boxes staged in LDS
#define NTX ((GW+TS-1)/TS)   // 7
#define NTY ((GH+TS-1)/TS)   // 7

// ---- Kernel 1: fused decode + suppression-mask build (tile + halo in LDS) ----
// For box j, predecessors (higher priority: score desc, index asc; IoU>0.4) all
// lie in the 3x3 cell neighborhood -> 45 slots -> one u64 bitmask per box.
__global__ __launch_bounds__(256) void decode_adj_kernel(
        const float* __restrict__ x, float* __restrict__ out,
        unsigned long long* __restrict__ masks, float* __restrict__ scores_g) {
    __shared__ float4 lbox[TBOX];
    __shared__ float  lsc[TBOX];
    int bx0 = (blockIdx.x % NTX) * TS;
    int by0 = (blockIdx.x / NTX) * TS;
    int tid = threadIdx.x;

    // Stage 1: decode halo tile into LDS (invalid cells -> sentinel score)
    for (int t = tid; t < TBOX; t += 256) {
        int lcell = t / NB, b = t % NB;
        int lx = lcell % HS, ly = lcell / HS;
        int gx = bx0 + lx - 1, gy = by0 + ly - 1;
        float4 bb = make_float4(0.f, 0.f, 0.f, 0.f);
        float s = -1e30f;                       // sentinel: never a predecessor
        if (gx >= 0 && gx < GW && gy >= 0 && gy < GH) {
            const float* p = x + ((size_t)(gy * GW + gx) * NB + b) * 5;
            float c0 = p[0], c1 = p[1], c2 = p[2], c3 = p[3]; s = p[4];
            float cx = (c0 + (float)gx) * SCALE;
            float w  = c2 * SCALE;
            float cy = NORMY - (c1 + (float)gy) * SCALE;
            float h  = c3 * SCALE;
            bb = make_float4(cx - w * 0.5f, cy - h * 0.5f,
                             cx + w * 0.5f, cy + h * 0.5f);
        }
        lbox[t] = bb; lsc[t] = s;
    }
    __syncthreads();

    // Stage 2: interior boxes -> write out[0:4]+score, build 45-bit mask
    for (int t = tid; t < TS * TS * NB; t += 256) {
        int lcell = t / NB, b = t % NB;
        int lxi = lcell % TS, lyi = lcell / TS;
        int gx = bx0 + lxi, gy = by0 + lyi;
        if (gx >= GW || gy >= GH) continue;
        int lt = ((lyi + 1) * HS + (lxi + 1)) * NB + b;
        float4 bj = lbox[lt]; float sj = lsc[lt];
        int j = (gy * GW + gx) * NB + b;
        float areaj = fmaxf(bj.z - bj.x, 0.f) * fmaxf(bj.w - bj.y, 0.f);
        unsigned long long m = 0ull;
        #pragma unroll
        for (int dy = -1; dy <= 1; ++dy)
        #pragma unroll
        for (int dx = -1; dx <= 1; ++dx)
        #pragma unroll
        for (int nb2 = 0; nb2 < NB; ++nb2) {
            int ln = ((lyi + 1 + dy) * HS + (lxi + 1 + dx)) * NB + nb2;
            int i = j + (dy * GW + dx) * NB + (nb2 - b);
            if (i == j) continue;
            float si = lsc[ln];
            // pri(i) > pri(j): score desc, stable-argsort index-asc tiebreak
            bool earlier = (si > sj) || (si == sj && i < j);
            if (!earlier) continue;
            float4 bi = lbox[ln];
            float iw = fmaxf(fminf(bi.z, bj.z) - fmaxf(bi.x, bj.x), 0.f);
            float ih = fmaxf(fminf(bi.w, bj.w) - fmaxf(bi.y, bj.y), 0.f);
            float inter = iw * ih;
            float areai = fmaxf(bi.z - bi.x, 0.f) * fmaxf(bi.w - bi.y, 0.f);
            float uni = areai + areaj - inter;
            float iou = (uni > 0.f) ? inter / fmaxf(uni, 1e-12f) : 0.f;
            if (iou > IOU_T)
                m |= 1ull << ((dy + 1) * 15 + (dx + 1) * 5 + nb2);
        }
        masks[j] = m;
        scores_g[j] = sj;
        out[j * 5 + 0] = bj.x; out[j * 5 + 1] = bj.y;
        out[j * 5 + 2] = bj.z; out[j * 5 + 3] = bj.w;
        out[j * 5 + 4] = sj;
    }
}

// ---- Kernel 2: chaotic fixpoint active[j] = NOR(active[preds]) -------------
// Masks cached in registers; pass loop touches only LDS + VALU.
// Correctness: boxes at suppression-DAG depth d are final after d passes
// under ANY interleaving (preds at depth<d already final during pass d).
__global__ __launch_bounds__(1024) void nms_kernel(
        const unsigned long long* __restrict__ masks,
        const float* __restrict__ scores, float* __restrict__ out) {
    __shared__ unsigned char act_s[NBOX];
    __shared__ int changed;
    int tid = threadIdx.x;

    unsigned long long cm[14];
    {
        int k = 0;
        for (int j = tid; j < NBOX; j += 1024) cm[k++] = masks[j];
    }
    for (int j = tid; j < NBOX; j += 1024) act_s[j] = 1;
    if (tid == 0) changed = 0;
    __syncthreads();

    volatile unsigned char* act = act_s;
    for (int pass = 0; pass < 256; ++pass) {
        bool mych = false;
        int k = 0;
        for (int j = tid; j < NBOX; j += 1024, ++k) {
            unsigned long long m = cm[k];
            int sup = 0;
            int base = j - j % NB;
            while (m) {
                int s = __builtin_ctzll(m); m &= m - 1;
                int dy = s / 15; int rem = s - dy * 15;
                int dx = rem / 5; int nb2 = rem - dx * 5;
                int i = base + ((dy - 1) * GW + (dx - 1)) * NB + nb2;
                sup |= act[i];
            }
            unsigned char na = sup ? 0 : 1;
            if (na != act[j]) { act[j] = na; mych = true; }
        }
        if (mych) changed = 1;
        __syncthreads();                 // updates + flag sets visible
        if ((pass & 3) == 3) {           // flag check every 4th pass
            int ch = changed;
            __syncthreads();             // all reads of flag done
            if (tid == 0) changed = 0;
            __syncthreads();             // reset visible before next sets
            if (!ch) break;              // uniform exit
        }
    }

    for (int j = tid; j < NBOX; j += 1024)
        out[j * 5 + 4] = act_s[j] ? scores[j] : 0.0f;
}

extern "C" void kernel_launch(void* const* d_in, const int* in_sizes, int n_in,
                              void* d_out, int out_size, void* d_ws, size_t ws_size,
                              hipStream_t stream) {
    const float* x = (const float*)d_in[0];
    float* out = (float*)d_out;

    // ws layout: masks u64[NBOX] | scores f32[NBOX]
    char* ws = (char*)d_ws;
    unsigned long long* masks = (unsigned long long*)ws;        // 108160 B
    float* scores = (float*)(ws + (size_t)NBOX * 8);            //  54080 B

    decode_adj_kernel<<<NTX * NTY, 256, 0, stream>>>(x, out, masks, scores);
    nms_kernel<<<1, 1024, 0, stream>>>(masks, scores, out);
}

// Round 3
// 90.928 us; speedup vs baseline: 1.3053x; 1.3053x over previous
//
#include <hip/hip_runtime.h>

#define GH 52
#define GW 52
#define NB 5
#define NCELL (GH*GW)        // 2704
#define NBOX (NCELL*NB)      // 13520
#define SCALE 8.0f           // 416/52
#define NORMY 416.0f
#define IOU_T 0.4f

#define TS 8                 // interior tile (cells)
#define HS (TS+2)            // halo tile 10x10
#define TBOX (HS*HS*NB)      // 500 boxes staged in LDS
#define NTX ((GW+TS-1)/TS)   // 7
#define NTY ((GH+TS-1)/TS)   // 7

#define PW (GW+2)            // padded act grid 54x54
#define PCELLS ((GH+2)*PW)   // 2916

// ---- Kernel 1: fused decode + suppression-mask build (tile + halo in LDS) ----
// For box j, predecessors (higher priority: score desc, index asc; IoU>0.4) all
// lie in the 3x3 cell neighborhood -> 45 slots -> one u64 bitmask per box.
// Slot layout: bit (dy+1)*15 + (dx+1)*5 + nb2  (matches nms V-vector build).
__global__ __launch_bounds__(256) void decode_adj_kernel(
        const float* __restrict__ x, float* __restrict__ out,
        unsigned long long* __restrict__ masks, float* __restrict__ scores_g) {
    __shared__ float4 lbox[TBOX];
    __shared__ float  lsc[TBOX];
    int bx0 = (blockIdx.x % NTX) * TS;
    int by0 = (blockIdx.x / NTX) * TS;
    int tid = threadIdx.x;

    // Stage 1: decode halo tile into LDS (invalid cells -> sentinel score)
    for (int t = tid; t < TBOX; t += 256) {
        int lcell = t / NB, b = t % NB;
        int lx = lcell % HS, ly = lcell / HS;
        int gx = bx0 + lx - 1, gy = by0 + ly - 1;
        float4 bb = make_float4(0.f, 0.f, 0.f, 0.f);
        float s = -1e30f;                       // sentinel: never a predecessor
        if (gx >= 0 && gx < GW && gy >= 0 && gy < GH) {
            const float* p = x + ((size_t)(gy * GW + gx) * NB + b) * 5;
            float c0 = p[0], c1 = p[1], c2 = p[2], c3 = p[3]; s = p[4];
            float cx = (c0 + (float)gx) * SCALE;
            float w  = c2 * SCALE;
            float cy = NORMY - (c1 + (float)gy) * SCALE;
            float h  = c3 * SCALE;
            bb = make_float4(cx - w * 0.5f, cy - h * 0.5f,
                             cx + w * 0.5f, cy + h * 0.5f);
        }
        lbox[t] = bb; lsc[t] = s;
    }
    __syncthreads();

    // Stage 2: interior boxes -> write out[0:4]+score, build 45-bit mask
    for (int t = tid; t < TS * TS * NB; t += 256) {
        int lcell = t / NB, b = t % NB;
        int lxi = lcell % TS, lyi = lcell / TS;
        int gx = bx0 + lxi, gy = by0 + lyi;
        if (gx >= GW || gy >= GH) continue;
        int lt = ((lyi + 1) * HS + (lxi + 1)) * NB + b;
        float4 bj = lbox[lt]; float sj = lsc[lt];
        int j = (gy * GW + gx) * NB + b;
        float areaj = fmaxf(bj.z - bj.x, 0.f) * fmaxf(bj.w - bj.y, 0.f);
        unsigned long long m = 0ull;
        #pragma unroll
        for (int dy = -1; dy <= 1; ++dy)
        #pragma unroll
        for (int dx = -1; dx <= 1; ++dx)
        #pragma unroll
        for (int nb2 = 0; nb2 < NB; ++nb2) {
            int ln = ((lyi + 1 + dy) * HS + (lxi + 1 + dx)) * NB + nb2;
            int i = j + (dy * GW + dx) * NB + (nb2 - b);
            if (i == j) continue;
            float si = lsc[ln];
            // pri(i) > pri(j): score desc, stable-argsort index-asc tiebreak
            bool earlier = (si > sj) || (si == sj && i < j);
            if (!earlier) continue;
            float4 bi = lbox[ln];
            float iw = fmaxf(fminf(bi.z, bj.z) - fmaxf(bi.x, bj.x), 0.f);
            float ih = fmaxf(fminf(bi.w, bj.w) - fmaxf(bi.y, bj.y), 0.f);
            float inter = iw * ih;
            float areai = fmaxf(bi.z - bi.x, 0.f) * fmaxf(bi.w - bi.y, 0.f);
            float uni = areai + areaj - inter;
            float iou = (uni > 0.f) ? inter / fmaxf(uni, 1e-12f) : 0.f;
            if (iou > IOU_T)
                m |= 1ull << ((dy + 1) * 15 + (dx + 1) * 5 + nb2);
        }
        masks[j] = m;
        scores_g[j] = sj;
        out[j * 5 + 0] = bj.x; out[j * 5 + 1] = bj.y;
        out[j * 5 + 2] = bj.z; out[j * 5 + 3] = bj.w;
        out[j * 5 + 4] = sj;
    }
}

// ---- Kernel 2: chaotic fixpoint active[j] = NOR(active[preds]) -------------
// act packed 5 bits/cell in a padded 54x54 byte grid (border = 0, masked off
// anyway since OOB slots have mask bit 0). Per cell per pass: 9 byte reads ->
// 45-bit neighborhood vector V; per box: suppressed = (V & mask) != 0.
// Chaotic iteration converges to the unique fixpoint (= exact greedy NMS) in
// <= DAG-depth passes under any interleaving.
__global__ __launch_bounds__(1024) void nms_kernel(
        const unsigned long long* __restrict__ masks,
        const float* __restrict__ scores, float* __restrict__ out) {
    __shared__ unsigned char act_s[PCELLS];
    int tid = threadIdx.x;

    // Masks for owned cells -> registers (cell ct = tid + k*1024)
    unsigned long long cm[3][NB];
    bool own[3];
    #pragma unroll
    for (int k = 0; k < 3; ++k) {
        int ct = tid + k * 1024;
        own[k] = (ct < NCELL);
        #pragma unroll
        for (int b = 0; b < NB; ++b)
            cm[k][b] = own[k] ? masks[ct * NB + b] : 0ull;
    }

    for (int i = tid; i < PCELLS; i += 1024) act_s[i] = 0;
    __syncthreads();
    for (int i = tid; i < NCELL; i += 1024) {
        int gy = i / GW, gx = i % GW;
        act_s[(gy + 1) * PW + (gx + 1)] = 0x1F;
    }
    __syncthreads();

    volatile unsigned char* act = act_s;

    for (int pass = 0; pass < 256; ++pass) {
        bool mych = false;
        #pragma unroll
        for (int k = 0; k < 3; ++k) {
            if (!own[k]) continue;
            int ct = tid + k * 1024;
            int gy = ct / GW, gx = ct % GW;
            int p0 = gy * PW + gx;               // top-left of 3x3 (padded coords)
            unsigned r0 = (unsigned)act[p0]          | ((unsigned)act[p0 + 1] << 5)
                        | ((unsigned)act[p0 + 2] << 10);
            unsigned r1 = (unsigned)act[p0 + PW]     | ((unsigned)act[p0 + PW + 1] << 5)
                        | ((unsigned)act[p0 + PW + 2] << 10);
            unsigned r2 = (unsigned)act[p0 + 2 * PW] | ((unsigned)act[p0 + 2 * PW + 1] << 5)
                        | ((unsigned)act[p0 + 2 * PW + 2] << 10);
            unsigned long long V = (unsigned long long)r0
                                 | ((unsigned long long)r1 << 15)
                                 | ((unsigned long long)r2 << 30);
            unsigned nb = 0;
            #pragma unroll
            for (int b = 0; b < NB; ++b)
                nb |= ((V & cm[k][b]) == 0ull ? 1u : 0u) << b;
            int pc = p0 + PW + 1;                // own cell (center)
            if ((unsigned char)nb != act[pc]) {
                act[pc] = (unsigned char)nb;
                mych = true;
            }
        }
        if (__syncthreads_count(mych ? 1 : 0) == 0) break;
    }

    // Writeback final scores
    #pragma unroll
    for (int k = 0; k < 3; ++k) {
        if (!own[k]) continue;
        int ct = tid + k * 1024;
        int gy = ct / GW, gx = ct % GW;
        unsigned bits = act_s[(gy + 1) * PW + (gx + 1)];
        #pragma unroll
        for (int b = 0; b < NB; ++b) {
            int j = ct * NB + b;
            out[j * 5 + 4] = ((bits >> b) & 1u) ? scores[j] : 0.0f;
        }
    }
}

extern "C" void kernel_launch(void* const* d_in, const int* in_sizes, int n_in,
                              void* d_out, int out_size, void* d_ws, size_t ws_size,
                              hipStream_t stream) {
    const float* x = (const float*)d_in[0];
    float* out = (float*)d_out;

    // ws layout: masks u64[NBOX] | scores f32[NBOX]
    char* ws = (char*)d_ws;
    unsigned long long* masks = (unsigned long long*)ws;        // 108160 B
    float* scores = (float*)(ws + (size_t)NBOX * 8);            //  54080 B

    decode_adj_kernel<<<NTX * NTY, 256, 0, stream>>>(x, out, masks, scores);
    nms_kernel<<<1, 1024, 0, stream>>>(masks, scores, out);
}

// Round 4
// 71.958 us; speedup vs baseline: 1.6494x; 1.2636x over previous
//
#include <hip/hip_runtime.h>

#define GH 52
#define GW 52
#define NB 5
#define NCELL (GH*GW)        // 2704
#define NBOX (NCELL*NB)      // 13520
#define SCALE 8.0f           // 416/52
#define NORMY 416.0f
#define IOU_T 0.4f

#define TS 4                 // interior tile (cells); 52 % 4 == 0 -> no partial tiles
#define HS (TS+2)            // halo tile 6x6
#define TBOX (HS*HS*NB)      // 180 boxes staged in LDS
#define NTX (GW/TS)          // 13
#define NTY (GH/TS)          // 13

#define PW (GW+2)            // padded act grid 54x54
#define PCELLS ((GH+2)*PW)   // 2916

// ---- Kernel 1: fused decode + suppression-mask build (tile + halo in LDS) ----
// For box j, predecessors (higher priority: score desc, index asc; IoU>0.4) all
// lie in the 3x3 cell neighborhood -> 45 slots -> one u64 bitmask per box.
// Slot layout: bit (dy+1)*15 + (dx+1)*5 + nb2  (matches nms V-vector build).
__global__ __launch_bounds__(192) void decode_adj_kernel(
        const float* __restrict__ x, float* __restrict__ out,
        unsigned long long* __restrict__ masks) {
    __shared__ float4 lbox[TBOX];
    __shared__ float  lsc[TBOX];
    int bx0 = (blockIdx.x % NTX) * TS;
    int by0 = (blockIdx.x / NTX) * TS;
    int t = threadIdx.x;

    // Stage 1: decode halo tile into LDS (one box/thread; invalid -> sentinel)
    if (t < TBOX) {
        int lcell = t / NB, b = t % NB;
        int lx = lcell % HS, ly = lcell / HS;
        int gx = bx0 + lx - 1, gy = by0 + ly - 1;
        float4 bb = make_float4(0.f, 0.f, 0.f, 0.f);
        float s = -1e30f;                       // sentinel: never a predecessor
        if (gx >= 0 && gx < GW && gy >= 0 && gy < GH) {
            const float* p = x + ((size_t)(gy * GW + gx) * NB + b) * 5;
            float c0 = p[0], c1 = p[1], c2 = p[2], c3 = p[3]; s = p[4];
            float cx = (c0 + (float)gx) * SCALE;
            float w  = c2 * SCALE;
            float cy = NORMY - (c1 + (float)gy) * SCALE;
            float h  = c3 * SCALE;
            bb = make_float4(cx - w * 0.5f, cy - h * 0.5f,
                             cx + w * 0.5f, cy + h * 0.5f);
        }
        lbox[t] = bb; lsc[t] = s;
    }
    __syncthreads();

    // Stage 2: interior boxes (one box/thread) -> out[0:5], 45-bit mask
    if (t < TS * TS * NB) {
        int lcell = t / NB, b = t % NB;
        int lxi = lcell % TS, lyi = lcell / TS;
        int gx = bx0 + lxi, gy = by0 + lyi;
        int lt = ((lyi + 1) * HS + (lxi + 1)) * NB + b;
        float4 bj = lbox[lt]; float sj = lsc[lt];
        int j = (gy * GW + gx) * NB + b;
        float areaj = fmaxf(bj.z - bj.x, 0.f) * fmaxf(bj.w - bj.y, 0.f);
        unsigned long long m = 0ull;
        #pragma unroll
        for (int dy = -1; dy <= 1; ++dy)
        #pragma unroll
        for (int dx = -1; dx <= 1; ++dx)
        #pragma unroll
        for (int nb2 = 0; nb2 < NB; ++nb2) {
            int ln = ((lyi + 1 + dy) * HS + (lxi + 1 + dx)) * NB + nb2;
            int i = j + (dy * GW + dx) * NB + (nb2 - b);
            if (i == j) continue;
            float si = lsc[ln];
            // pri(i) > pri(j): score desc, stable-argsort index-asc tiebreak
            bool earlier = (si > sj) || (si == sj && i < j);
            if (!earlier) continue;
            float4 bi = lbox[ln];
            float iw = fmaxf(fminf(bi.z, bj.z) - fmaxf(bi.x, bj.x), 0.f);
            float ih = fmaxf(fminf(bi.w, bj.w) - fmaxf(bi.y, bj.y), 0.f);
            float inter = iw * ih;
            float areai = fmaxf(bi.z - bi.x, 0.f) * fmaxf(bi.w - bi.y, 0.f);
            float uni = areai + areaj - inter;
            float iou = (uni > 0.f) ? inter / fmaxf(uni, 1e-12f) : 0.f;
            if (iou > IOU_T)
                m |= 1ull << ((dy + 1) * 15 + (dx + 1) * 5 + nb2);
        }
        masks[j] = m;
        out[j * 5 + 0] = bj.x; out[j * 5 + 1] = bj.y;
        out[j * 5 + 2] = bj.z; out[j * 5 + 3] = bj.w;
        out[j * 5 + 4] = sj;
    }
}

// ---- Kernel 2: chaotic fixpoint active[j] = NOR(active[preds]) -------------
// act packed 5 bits/cell in padded 54x54 byte grid. Per cell per pass:
// 9 byte reads -> 45-bit neighborhood vector V; per box: sup = (V & mask)!=0.
// Row-dirty gating (exact): a cell is re-evaluated only if one of its 3
// neighbor rows changed last pass; unchanged neighborhood => identical eval.
// Chaotic iteration converges to the unique DAG fixpoint (= exact greedy NMS).
__global__ __launch_bounds__(1024) void nms_kernel(
        const unsigned long long* __restrict__ masks,
        float* __restrict__ out) {
    __shared__ unsigned char act_s[PCELLS];
    __shared__ unsigned int rowflag[2][GH + 2];   // [parity][row+1], double-buffered
    int tid = threadIdx.x;

    // Masks for owned cells -> registers (cell ct = tid + k*1024, strided)
    unsigned long long cm[3][NB];
    bool own[3];
    #pragma unroll
    for (int k = 0; k < 3; ++k) {
        int ct = tid + k * 1024;
        own[k] = (ct < NCELL);
        #pragma unroll
        for (int b = 0; b < NB; ++b)
            cm[k][b] = own[k] ? masks[ct * NB + b] : 0ull;
    }

    for (int i = tid; i < PCELLS; i += 1024) act_s[i] = 0;
    if (tid < GH + 2) {
        rowflag[0][tid] = 0;
        rowflag[1][tid] = (tid >= 1 && tid <= GH) ? 1u : 0u;  // prev for pass 0: all dirty
    }
    __syncthreads();
    for (int i = tid; i < NCELL; i += 1024) {
        int gy = i / GW, gx = i % GW;
        act_s[(gy + 1) * PW + (gx + 1)] = 0x1F;
    }
    __syncthreads();

    volatile unsigned char* act = act_s;

    int par = 0;   // cur = rowflag[par], prev = rowflag[par^1]
    for (int pass = 0; pass < 256; ++pass) {
        // clear cur flags (holds stale flags from 2 passes ago)
        if (tid < GH + 2) rowflag[par][tid] = 0;
        __syncthreads();
        const unsigned int* prevf = rowflag[par ^ 1];
        bool mych = false;
        #pragma unroll
        for (int k = 0; k < 3; ++k) {
            if (!own[k]) continue;
            int ct = tid + k * 1024;
            int gy = ct / GW, gx = ct % GW;
            if ((prevf[gy] | prevf[gy + 1] | prevf[gy + 2]) == 0u) continue;
            int p0 = gy * PW + gx;               // top-left of 3x3 (padded coords)
            unsigned r0 = (unsigned)act[p0]          | ((unsigned)act[p0 + 1] << 5)
                        | ((unsigned)act[p0 + 2] << 10);
            unsigned r1 = (unsigned)act[p0 + PW]     | ((unsigned)act[p0 + PW + 1] << 5)
                        | ((unsigned)act[p0 + PW + 2] << 10);
            unsigned r2 = (unsigned)act[p0 + 2 * PW] | ((unsigned)act[p0 + 2 * PW + 1] << 5)
                        | ((unsigned)act[p0 + 2 * PW + 2] << 10);
            unsigned long long V = (unsigned long long)r0
                                 | ((unsigned long long)r1 << 15)
                                 | ((unsigned long long)r2 << 30);
            unsigned nb = 0;
            #pragma unroll
            for (int b = 0; b < NB; ++b)
                nb |= ((V & cm[k][b]) == 0ull ? 1u : 0u) << b;
            int pc = p0 + PW + 1;                // own cell (center)
            if ((unsigned char)nb != act[pc]) {
                act[pc] = (unsigned char)nb;
                atomicOr(&rowflag[par][gy + 1], 1u);
                mych = true;
            }
        }
        if (__syncthreads_count(mych ? 1 : 0) == 0) break;
        par ^= 1;
    }

    // Writeback: zero scores of suppressed boxes (score was stored in out by k1)
    #pragma unroll
    for (int k = 0; k < 3; ++k) {
        if (!own[k]) continue;
        int ct = tid + k * 1024;
        int gy = ct / GW, gx = ct % GW;
        unsigned bits = act_s[(gy + 1) * PW + (gx + 1)];
        #pragma unroll
        for (int b = 0; b < NB; ++b) {
            int j = ct * NB + b;
            if (!((bits >> b) & 1u)) out[j * 5 + 4] = 0.0f;
        }
    }
}

extern "C" void kernel_launch(void* const* d_in, const int* in_sizes, int n_in,
                              void* d_out, int out_size, void* d_ws, size_t ws_size,
                              hipStream_t stream) {
    const float* x = (const float*)d_in[0];
    float* out = (float*)d_out;

    // ws layout: masks u64[NBOX]
    unsigned long long* masks = (unsigned long long*)d_ws;      // 108160 B

    decode_adj_kernel<<<NTX * NTY, 192, 0, stream>>>(x, out, masks);
    nms_kernel<<<1, 1024, 0, stream>>>(masks, out);
}

// Round 5
// 71.886 us; speedup vs baseline: 1.6510x; 1.0010x over previous
//
#include <hip/hip_runtime.h>

#define GH 52
#define GW 52
#define NB 5
#define NCELL (GH*GW)        // 2704
#define NBOX (NCELL*NB)      // 13520
#define SCALE 8.0f           // 416/52
#define NORMY 416.0f
#define IOU_T 0.4f

#define TS 4                 // interior tile (cells); 52 % 4 == 0 -> no partial tiles
#define HS (TS+2)            // halo tile 6x6
#define TBOX (HS*HS*NB)      // 180 boxes staged in LDS
#define NTX (GW/TS)          // 13
#define NTY (GH/TS)          // 13

#define PW (GW+2)            // padded act grid 54x54
#define PCELLS ((GH+2)*PW)   // 2916

// ---- Kernel 1: fused decode + suppression-mask build (tile + halo in LDS) ----
// For box j, predecessors (higher priority: score desc, index asc; IoU>0.4) all
// lie in the 3x3 cell neighborhood -> 45 slots -> one u64 bitmask per box.
// Slot layout: bit (dy+1)*15 + (dx+1)*5 + nb2  (matches nms V-vector build).
// Masks stored plane-major: masks[b*NCELL + cell] for coalesced nms preload.
__global__ __launch_bounds__(192) void decode_adj_kernel(
        const float* __restrict__ x, float* __restrict__ out,
        unsigned long long* __restrict__ masks) {
    __shared__ float4 lbox[TBOX];
    __shared__ float  lsc[TBOX];
    int bx0 = (blockIdx.x % NTX) * TS;
    int by0 = (blockIdx.x / NTX) * TS;
    int t = threadIdx.x;

    // Stage 1: decode halo tile into LDS (one box/thread; invalid -> sentinel)
    if (t < TBOX) {
        int lcell = t / NB, b = t % NB;
        int lx = lcell % HS, ly = lcell / HS;
        int gx = bx0 + lx - 1, gy = by0 + ly - 1;
        float4 bb = make_float4(0.f, 0.f, 0.f, 0.f);
        float s = -1e30f;                       // sentinel: never a predecessor
        if (gx >= 0 && gx < GW && gy >= 0 && gy < GH) {
            const float* p = x + ((size_t)(gy * GW + gx) * NB + b) * 5;
            float c0 = p[0], c1 = p[1], c2 = p[2], c3 = p[3]; s = p[4];
            float cx = (c0 + (float)gx) * SCALE;
            float w  = c2 * SCALE;
            float cy = NORMY - (c1 + (float)gy) * SCALE;
            float h  = c3 * SCALE;
            bb = make_float4(cx - w * 0.5f, cy - h * 0.5f,
                             cx + w * 0.5f, cy + h * 0.5f);
        }
        lbox[t] = bb; lsc[t] = s;
    }
    __syncthreads();

    // Stage 2: interior boxes (one box/thread) -> out[0:5], 45-bit mask
    if (t < TS * TS * NB) {
        int lcell = t / NB, b = t % NB;
        int lxi = lcell % TS, lyi = lcell / TS;
        int gx = bx0 + lxi, gy = by0 + lyi;
        int lt = ((lyi + 1) * HS + (lxi + 1)) * NB + b;
        float4 bj = lbox[lt]; float sj = lsc[lt];
        int cell = gy * GW + gx;
        int j = cell * NB + b;
        float areaj = fmaxf(bj.z - bj.x, 0.f) * fmaxf(bj.w - bj.y, 0.f);
        unsigned long long m = 0ull;
        #pragma unroll
        for (int dy = -1; dy <= 1; ++dy)
        #pragma unroll
        for (int dx = -1; dx <= 1; ++dx)
        #pragma unroll
        for (int nb2 = 0; nb2 < NB; ++nb2) {
            int ln = ((lyi + 1 + dy) * HS + (lxi + 1 + dx)) * NB + nb2;
            int i = j + (dy * GW + dx) * NB + (nb2 - b);
            if (i == j) continue;
            float si = lsc[ln];
            // pri(i) > pri(j): score desc, stable-argsort index-asc tiebreak
            bool earlier = (si > sj) || (si == sj && i < j);
            if (!earlier) continue;
            float4 bi = lbox[ln];
            float iw = fmaxf(fminf(bi.z, bj.z) - fmaxf(bi.x, bj.x), 0.f);
            float ih = fmaxf(fminf(bi.w, bj.w) - fmaxf(bi.y, bj.y), 0.f);
            float inter = iw * ih;
            float areai = fmaxf(bi.z - bi.x, 0.f) * fmaxf(bi.w - bi.y, 0.f);
            float uni = areai + areaj - inter;
            float iou = (uni > 0.f) ? inter / fmaxf(uni, 1e-12f) : 0.f;
            if (iou > IOU_T)
                m |= 1ull << ((dy + 1) * 15 + (dx + 1) * 5 + nb2);
        }
        masks[b * NCELL + cell] = m;
        out[j * 5 + 0] = bj.x; out[j * 5 + 1] = bj.y;
        out[j * 5 + 2] = bj.z; out[j * 5 + 3] = bj.w;
        out[j * 5 + 4] = sj;
    }
}

// ---- Kernel 2: chaotic fixpoint active[j] = NOR(active[preds]) -------------
// act packed 5 bits/cell in padded 54x54 byte grid. Per cell per pass:
// 9 byte reads -> 45-bit neighborhood vector V; per box: sup = (V & mask)!=0.
// Row-dirty gating (exact): cell re-evaluated only if one of its 3 neighbor
// rows changed last pass. 3-buffer flag rotation: clear of next-pass buffer
// overlaps evaluation -> single barrier per pass (__syncthreads_count).
// Chaotic iteration converges to the unique DAG fixpoint (= exact greedy NMS).
__global__ __launch_bounds__(1024) void nms_kernel(
        const unsigned long long* __restrict__ masks,
        float* __restrict__ out) {
    __shared__ unsigned char act_s[PCELLS];
    __shared__ unsigned int rowflag[3][GH + 2];
    int tid = threadIdx.x;

    // Masks for owned cells -> registers; plane-major = coalesced 8B/lane
    unsigned long long cm[3][NB];
    bool own[3];
    #pragma unroll
    for (int k = 0; k < 3; ++k) {
        int ct = tid + k * 1024;
        own[k] = (ct < NCELL);
        #pragma unroll
        for (int b = 0; b < NB; ++b)
            cm[k][b] = own[k] ? masks[b * NCELL + ct] : 0ull;
    }

    for (int i = tid; i < PCELLS; i += 1024) act_s[i] = 0;
    if (tid < GH + 2) {
        rowflag[0][tid] = 0;                                   // cur  for pass 0
        rowflag[1][tid] = 0;                                   // next for pass 0
        rowflag[2][tid] = (tid >= 1 && tid <= GH) ? 1u : 0u;   // prev for pass 0: all dirty
    }
    __syncthreads();
    for (int i = tid; i < NCELL; i += 1024) {
        int gy = i / GW, gx = i % GW;
        act_s[(gy + 1) * PW + (gx + 1)] = 0x1F;
    }
    __syncthreads();

    volatile unsigned char* act = act_s;

    int pprev = 2, pcur = 0, pnext = 1;
    for (int pass = 0; pass < 256; ++pass) {
        // clear next-pass buffer (not read/written this pass -> no barrier needed)
        if (tid < GH + 2) rowflag[pnext][tid] = 0;
        const unsigned int* prevf = rowflag[pprev];
        bool mych = false;
        #pragma unroll
        for (int k = 0; k < 3; ++k) {
            if (!own[k]) continue;
            int ct = tid + k * 1024;
            int gy = ct / GW, gx = ct % GW;
            if ((prevf[gy] | prevf[gy + 1] | prevf[gy + 2]) == 0u) continue;
            int p0 = gy * PW + gx;               // top-left of 3x3 (padded coords)
            unsigned r0 = (unsigned)act[p0]          | ((unsigned)act[p0 + 1] << 5)
                        | ((unsigned)act[p0 + 2] << 10);
            unsigned r1 = (unsigned)act[p0 + PW]     | ((unsigned)act[p0 + PW + 1] << 5)
                        | ((unsigned)act[p0 + PW + 2] << 10);
            unsigned r2 = (unsigned)act[p0 + 2 * PW] | ((unsigned)act[p0 + 2 * PW + 1] << 5)
                        | ((unsigned)act[p0 + 2 * PW + 2] << 10);
            unsigned long long V = (unsigned long long)r0
                                 | ((unsigned long long)r1 << 15)
                                 | ((unsigned long long)r2 << 30);
            unsigned nb = 0;
            #pragma unroll
            for (int b = 0; b < NB; ++b)
                nb |= ((V & cm[k][b]) == 0ull ? 1u : 0u) << b;
            int pc = p0 + PW + 1;                // own cell (center)
            if ((unsigned char)nb != act[pc]) {
                act[pc] = (unsigned char)nb;
                atomicOr(&rowflag[pcur][gy + 1], 1u);
                mych = true;
            }
        }
        if (__syncthreads_count(mych ? 1 : 0) == 0) break;
        int t0 = pprev; pprev = pcur; pcur = pnext; pnext = t0;
    }

    // Writeback: zero scores of suppressed boxes (score was stored in out by k1)
    #pragma unroll
    for (int k = 0; k < 3; ++k) {
        if (!own[k]) continue;
        int ct = tid + k * 1024;
        int gy = ct / GW, gx = ct % GW;
        unsigned bits = act_s[(gy + 1) * PW + (gx + 1)];
        #pragma unroll
        for (int b = 0; b < NB; ++b) {
            int j = ct * NB + b;
            if (!((bits >> b) & 1u)) out[j * 5 + 4] = 0.0f;
        }
    }
}

extern "C" void kernel_launch(void* const* d_in, const int* in_sizes, int n_in,
                              void* d_out, int out_size, void* d_ws, size_t ws_size,
                              hipStream_t stream) {
    const float* x = (const float*)d_in[0];
    float* out = (float*)d_out;

    // ws layout: masks u64[NB][NCELL] (plane-major)
    unsigned long long* masks = (unsigned long long*)d_ws;      // 108160 B

    decode_adj_kernel<<<NTX * NTY, 192, 0, stream>>>(x, out, masks);
    nms_kernel<<<1, 1024, 0, stream>>>(masks, out);
}